// Round 6
// baseline (373.298 us; speedup 1.0000x reference)
//
#include <hip/hip_runtime.h>
#include <stdint.h>

// LSTM autoencoder B=32768 T=30 I=4 H=64 L=32, fp32 in/out.
// v19 = v18 (4 waves/SIMD, 261us) + LDS-BANDWIDTH CUT.
// v18 post-mortem: occupancy 21->38% with dur WORSE and VALUBusy pinned ~59%
// -> stall is a shared per-CU resource. Counting b128 frag reads: v18 ~35
// (enc) / ~66 (dec) per wave-step x 16 waves/CU x ~12cy = ~600K cy/CU
// = 250us ~= measured 261us: the LDS READ PIPE was saturated (same math
// puts v14 at ~215us vs 235 measured). v15-17 were the other wall
// (latency at 2 w/SIMD). v19 keeps 4 w/SIMD and halves in-loop LDS traffic:
//  - enc: hoist own-half Whh1 frags to regs (16 x bf16x8 = 64 VGPR);
//    W1C x-fold tile becomes an in-loop b64 read + 5-select expand
//    (frees the 32-VGPR w1a hoist; net VGPR ~96-112 < 128 cliff).
//  - dec: hoist own-half Whh3 frags (64 VGPR, reuses dead enc regs).
// Predicted LDS: enc 35->~21, dec 66->~14 b128-eq/wave-step => ~87us/CU.
// Structure/math otherwise identical to v18: 2-wave halves per 16-batch
// group, 2 syncthreads/step, 2 blocks/CU (LDS 80448B), 1-term bf16 h,
// 2-term x + 2-term bias in MFMA k-slots, log2e folded into weights,
// unitH = 5 exp2 + 2 rcp. absmax 9.77e-4.
// Layouts (HW-verified): C/D col=lane&15(batch), row=(lane>>4)*4+reg(unit)
// [m89]; A/B m|n=lane&15, k=(lane>>4)*8+j [m120].

typedef unsigned short u16;
typedef unsigned int u32;
typedef __attribute__((ext_vector_type(8))) short bf16x8;
typedef __attribute__((ext_vector_type(4))) float f32x4;
typedef __attribute__((ext_vector_type(4))) u32 u32x4;
typedef __attribute__((ext_vector_type(2))) u32 u32x2;

#define BATCH 32768
#define TT 30
#define IN 4
#define WAVES 8
#define BLOCKT (WAVES * 64)   // 512
#define MB 16                 // batches per group
#define NGRP 4                // groups per block (2 waves each)
#define BPB (NGRP * MB)       // 64 -> grid 512, 2 blocks/CU

#define LOG2E 1.4426950408889634f
#define LOG2E2 2.8853900817779268f

// ---- LDS word offsets ----
// enc weights (0..16383)
#define O_WHH1 0        // 8192
#define O_W1C  8192     // 2048 (256 rows x 16 u16: whi4|wlo4|bhi|blo|0x6)
#define O_WIH2 10240    // 4096
#define O_WHH2 14336    // 2048 -> 16384
// dec weights (same region, restaged)
#define O_WHH3 0        // 8192
#define O_WIH3 8192     // 4096
#define O_WIH4 12288    // 512
#define O_W4HHF 12800   // 64 -> 12864
// biases (survive restage)
#define O_B2F 16384     // 128
#define O_B3F 16512     // 256
#define O_B4F 16768     // 16
#define O_BUFS 16784
// per-group: h1/h3 512w | h2/latent 256w (gbuf aliases in dec) | h4 64w
#define PBUF 832
#define SMEM_WORDS (O_BUFS + NGRP * PBUF)   // 20112
#define SMEM_BYTES (SMEM_WORDS * 4)         // 80448 -> 2 blocks/CU (160896<=163840)

#define WB() __builtin_amdgcn_wave_barrier()
// arg order: A = weight frag, B = data frag.
#define MFMA(a, b, c) __builtin_amdgcn_mfma_f32_16x16x32_bf16((a), (b), (c), 0, 0, 0)

__device__ __forceinline__ u16 f2bf(float f) {   // RNE fp32->bf16 (staging)
    u32 u = __float_as_uint(f);
    u += 0x7fffu + ((u >> 16) & 1u);
    return (u16)(u >> 16);
}
__device__ __forceinline__ float bf2f(u16 v) { return __uint_as_float(((u32)v) << 16); }

__device__ __forceinline__ u32 cvtpk2(float a, float b) {   // packed RNE fp32x2->bf16x2
    u32 d;
    asm("v_cvt_pk_bf16_f32 %0, %1, %2" : "=v"(d) : "v"(a), "v"(b));
    return d;
}

// Fused LSTM cell update. Inputs pre-scaled (i,f,o by log2e; g by 2*log2e).
__device__ __forceinline__ float unitH(float yi, float yf, float yg, float yo, float& c) {
    const float ei = __builtin_amdgcn_exp2f(-yi);
    const float ef = __builtin_amdgcn_exp2f(-yf);
    const float eg = __builtin_amdgcn_exp2f(yg);
    const float eo = __builtin_amdgcn_exp2f(-yo);
    const float Z = (1.f + ei) * (1.f + eg);
    const float X = 1.f + ef;
    const float num = fmaf(eg - 1.f, X, c * Z);
    c = num * __builtin_amdgcn_rcpf(X * Z);
    const float ec = __builtin_amdgcn_exp2f(c * LOG2E2);
    return (ec - 1.f) * __builtin_amdgcn_rcpf((1.f + eo) * (1.f + ec));
}

// Stage fp32 W[N][K] -> bf16 hi, fragment order, rows pre-scaled by gate factor.
template <int KT, int GS>
__device__ __forceinline__ void stageBh(u16* hi, const float* src, int N, int tid) {
    const int K = KT * 32;
    const int total = N * K;
    for (int idx = tid; idx < total; idx += BLOCKT) {
        const int j = idx & 7;
        const int l = (idx >> 3) & 63;
        const int pr = idx >> 9;
        const int kt = pr & (KT - 1);
        const int nt = pr / KT;
        const int n = (nt << 4) | (l & 15);
        const int k = (kt << 5) + ((l >> 4) << 3) + j;
        const float s = (((n >> GS) & 3) == 2) ? LOG2E2 : LOG2E;
        hi[idx] = f2bf(src[n * K + k] * s);
    }
}

__global__ __launch_bounds__(BLOCKT)
__attribute__((amdgpu_waves_per_eu(4)))
void lstm_ae(
    const float* __restrict__ x,
    const float* __restrict__ w1ih, const float* __restrict__ w1hh,
    const float* __restrict__ b1i, const float* __restrict__ b1h,
    const float* __restrict__ w2ih, const float* __restrict__ w2hh,
    const float* __restrict__ b2i, const float* __restrict__ b2h,
    const float* __restrict__ w3ih, const float* __restrict__ w3hh,
    const float* __restrict__ b3i, const float* __restrict__ b3h,
    const float* __restrict__ w4ih, const float* __restrict__ w4hh,
    const float* __restrict__ b4i, const float* __restrict__ b4h,
    float* __restrict__ out) {
    extern __shared__ float smem[];
    float* W = smem;

    const int tid = threadIdx.x;
    const int wave = tid >> 6, lane = tid & 63;
    const int wg = wave >> 1, wh = wave & 1;   // group, half
    const int col = lane & 15, quad = lane >> 4;
    const int q0 = wh << 1;                    // unit-quarter base for this half

    float* pb = smem + O_BUFS + wg * PBUF;
    u16* h1b = (u16*)pb;             // 1024 u16: h1 (enc) / h3 (dec), single buf
    u16* h2b = (u16*)(pb + 512);     // 512 u16: h2 / latent (enc)
    float* gbuf = pb + 512;          // 256 f: dec2 gate transpose (aliases h2b)
    float* bufH4 = pb + 768;         // 64 f: dec2 h feedback

    const int b0w = blockIdx.x * BPB + wg * MB;
    const int hbase = (col << 3) + ((quad & 1) << 2) + ((quad >> 1) << 7);

    // ---------------- stage ENCODER weights + biases ----------------
    stageBh<2, 6>((u16*)(W + O_WHH1), w1hh, 256, tid);
    stageBh<2, 5>((u16*)(W + O_WIH2), w2ih, 128, tid);
    stageBh<1, 5>((u16*)(W + O_WHH2), w2hh, 128, tid);
    {   // W1C rows (16 u16): [whi0-3 | wlo0-3 | bhi | blo | 0 x6]
        u16* C = (u16*)(W + O_W1C);
        for (int idx = tid; idx < 256 * 16; idx += BLOCKT) {
            const int n = idx >> 4, j = idx & 15;
            const float sc = ((n >> 6) == 2) ? LOG2E2 : LOG2E;
            u16 v = 0;
            if (j < 4) {
                v = f2bf(w1ih[n * 4 + j] * sc);
            } else if (j < 8) {
                const float w = w1ih[n * 4 + (j - 4)] * sc;
                v = f2bf(w - bf2f(f2bf(w)));
            } else if (j == 8) {
                v = f2bf((b1i[n] + b1h[n]) * sc);
            } else if (j == 9) {
                const float b = (b1i[n] + b1h[n]) * sc;
                v = f2bf(b - bf2f(f2bf(b)));
            }
            C[idx] = v;
        }
    }
    float* b2f = W + O_B2F;
    float* b3f = W + O_B3F;
    float* b4f = W + O_B4F;
    for (int i = tid; i < 128; i += BLOCKT)
        b2f[i] = (b2i[i] + b2h[i]) * (((i >> 5) == 2) ? LOG2E2 : LOG2E);
    for (int i = tid; i < 256; i += BLOCKT)
        b3f[i] = (b3i[i] + b3h[i]) * (((i >> 6) == 2) ? LOG2E2 : LOG2E);
    for (int i = tid; i < 16; i += BLOCKT)
        b4f[i] = (b4i[i] + b4h[i]) * (((i >> 2) == 2) ? LOG2E2 : LOG2E);
    {   // zero h2 + h4 (h1 needs no zero: prologue writes full image)
        u32* z = (u32*)pb;
        if (wh == 0) {
            for (int i = lane; i < 256; i += 64) z[512 + i] = 0u;
        } else {
            bufH4[lane] = 0.f;
        }
    }
    __syncthreads();

    const u16* Whh1hi = (const u16*)(W + O_WHH1);
    const u16* Wih2hi = (const u16*)(W + O_WIH2);
    const u16* Whh2hi = (const u16*)(W + O_WHH2);
    // per-lane row base into W1C (row = nt*16+col, 16 u16 each); quad offset
    const u16* W1cX = (const u16*)(W + O_W1C) + (col << 4);
    const int woff = (quad == 1) ? 4 : ((quad >= 2) ? 8 : 0);

    // ---- hoist own-half Whh1 frags to regs (16 x bf16x8 = 64 VGPR) ----
    bf16x8 whh1r[2][4][2];
#pragma unroll
    for (int ql = 0; ql < 2; ++ql)
#pragma unroll
        for (int i = 0; i < 4; ++i) {
            const int nt = i * 4 + q0 + ql;
            whh1r[ql][i][0] = *reinterpret_cast<const bf16x8*>(Whh1hi + ((nt * 2 + 0) * 64 + lane) * 8);
            whh1r[ql][i][1] = *reinterpret_cast<const bf16x8*>(Whh1hi + ((nt * 2 + 1) * 64 + lane) * 8);
        }

    // ================= encoder =================
    float c1[2][4];   // this half's unit-quarters
    float c2v[4];     // this half's enc2 quarter
#pragma unroll
    for (int ql = 0; ql < 2; ++ql)
#pragma unroll
        for (int r = 0; r < 4; ++r) c1[ql][r] = 0.f;
#pragma unroll
    for (int r = 0; r < 4; ++r) c2v[r] = 0.f;

    const f32x4 zf = {0.f, 0.f, 0.f, 0.f};
    float4 xcur = *reinterpret_cast<const float4*>(x + ((size_t)(b0w + col) * TT + 0) * IN);

    // x B-frag: quad0 [xhi,xlo], quad1 [xhi,0], quad2 [1.0 1.0 (bias slots)], quad3 0
    auto buildX = [&](const float4 xc) -> bf16x8 {
        const u32 hi01 = cvtpk2(xc.x, xc.y);
        const u32 hi23 = cvtpk2(xc.z, xc.w);
        const float r0 = xc.x - __uint_as_float(hi01 << 16);
        const float r1 = xc.y - __uint_as_float(hi01 & 0xffff0000u);
        const float r2 = xc.z - __uint_as_float(hi23 << 16);
        const float r3 = xc.w - __uint_as_float(hi23 & 0xffff0000u);
        const u32 lo01 = cvtpk2(r0, r1);
        const u32 lo23 = cvtpk2(r2, r3);
        u32x4 xv;
        xv.x = (quad <= 1) ? hi01 : ((quad == 2) ? 0x3F803F80u : 0u);
        xv.y = (quad <= 1) ? hi23 : 0u;
        xv.z = (quad == 0) ? lo01 : 0u;
        xv.w = (quad == 0) ? lo23 : 0u;
        return __builtin_bit_cast(bf16x8, xv);
    };
    // build the Wih1-fold A-frag for tile nt from its W1C row (1 b64 read):
    //   q0=[whi,whi], q1=[wlo,wlo], q2=[bhi,blo,0..], q3=0
    auto buildW1 = [&](int nt) -> bf16x8 {
        const u32x2 p = *reinterpret_cast<const u32x2*>(W1cX + (nt << 8) + woff);
        u32x4 v;
        v.x = (quad == 3) ? 0u : p.x;
        v.y = (quad <= 1) ? p.y : 0u;
        v.z = (quad <= 1) ? p.x : 0u;
        v.w = (quad <= 1) ? p.y : 0u;
        return __builtin_bit_cast(bf16x8, v);
    };

    // enc1 for this half: 24 MFMA + 8 unitH, writes own h1 half
    auto enc1_half = [&](const bf16x8 a1x, const bf16x8 ah0, const bf16x8 ah1) {
#pragma unroll
        for (int ql = 0; ql < 2; ++ql) {
            f32x4 acc[4];
#pragma unroll
            for (int i = 0; i < 4; ++i) {
                const int nt = i * 4 + q0 + ql;
                f32x4 a = MFMA(buildW1(nt), a1x, zf);
                a = MFMA(whh1r[ql][i][0], ah0, a);
                a = MFMA(whh1r[ql][i][1], ah1, a);
                acc[i] = a;
            }
            const float h0 = unitH(acc[0][0], acc[1][0], acc[2][0], acc[3][0], c1[ql][0]);
            const float h1 = unitH(acc[0][1], acc[1][1], acc[2][1], acc[3][1], c1[ql][1]);
            const float h2 = unitH(acc[0][2], acc[1][2], acc[2][2], acc[3][2], c1[ql][2]);
            const float h3 = unitH(acc[0][3], acc[1][3], acc[2][3], acc[3][3], c1[ql][3]);
            u32x2 wv;
            wv.x = cvtpk2(h0, h1);
            wv.y = cvtpk2(h2, h3);
            *reinterpret_cast<u32x2*>(h1b + hbase + (wh << 9) + (ql << 8)) = wv;
        }
    };
    // enc2 for this half: 12 MFMA + 4 unitH, writes own h2 half
    auto enc2_half = [&](const bf16x8 ah0, const bf16x8 ah1, const bf16x8 a2h) {
        f32x4 g4[4];
#pragma unroll
        for (int g = 0; g < 4; ++g) {
            const int nt = g * 2 + wh;
            const bf16x8 bh0 = *reinterpret_cast<const bf16x8*>(Wih2hi + ((nt * 2 + 0) * 64 + lane) * 8);
            const bf16x8 bh1 = *reinterpret_cast<const bf16x8*>(Wih2hi + ((nt * 2 + 1) * 64 + lane) * 8);
            const bf16x8 ch = *reinterpret_cast<const bf16x8*>(Whh2hi + (nt * 64 + lane) * 8);
            f32x4 a = *reinterpret_cast<const f32x4*>(b2f + nt * 16 + (quad << 2));
            a = MFMA(bh0, ah0, a);
            a = MFMA(bh1, ah1, a);
            a = MFMA(ch, a2h, a);
            g4[g] = a;
        }
        const float h0 = unitH(g4[0][0], g4[1][0], g4[2][0], g4[3][0], c2v[0]);
        const float h1 = unitH(g4[0][1], g4[1][1], g4[2][1], g4[3][1], c2v[1]);
        const float h2 = unitH(g4[0][2], g4[1][2], g4[2][2], g4[3][2], c2v[2]);
        const float h3 = unitH(g4[0][3], g4[1][3], g4[2][3], g4[3][3], c2v[3]);
        u32x2 wv;
        wv.x = cvtpk2(h0, h1);
        wv.y = cvtpk2(h2, h3);
        *reinterpret_cast<u32x2*>(h2b + hbase + (wh << 8)) = wv;
    };

    {   // prologue: enc1[0] with h1[-1]=0
        const bf16x8 z8 = {};
        const bf16x8 a1x = buildX(xcur);
        xcur = *reinterpret_cast<const float4*>(x + ((size_t)(b0w + col) * TT + 1) * IN);
        enc1_half(a1x, z8, z8);
    }
    __syncthreads();

    for (int t = 0; t < TT - 1; ++t) {
        // reads (before alpha)
        const bf16x8 ah0 = *reinterpret_cast<const bf16x8*>(h1b + lane * 8);        // h1[t]
        const bf16x8 ah1 = *reinterpret_cast<const bf16x8*>(h1b + (64 + lane) * 8);
        const bf16x8 a2h = *reinterpret_cast<const bf16x8*>(h2b + lane * 8);        // h2[t-1]
        __syncthreads();   // alpha: all reads done before any writes
        enc2_half(ah0, ah1, a2h);                    // writes h2[t] half
        const bf16x8 a1x = buildX(xcur);
        {
            const int tn = (t + 2 < TT) ? t + 2 : TT - 1;
            xcur = *reinterpret_cast<const float4*>(x + ((size_t)(b0w + col) * TT + tn) * IN);
        }
        enc1_half(a1x, ah0, ah1);                    // writes h1[t+1] half
        __syncthreads();   // beta: writes visible for next step's reads
    }
    {   // epilogue: enc2[TT-1] -> latent
        const bf16x8 ah0 = *reinterpret_cast<const bf16x8*>(h1b + lane * 8);
        const bf16x8 ah1 = *reinterpret_cast<const bf16x8*>(h1b + (64 + lane) * 8);
        const bf16x8 a2h = *reinterpret_cast<const bf16x8*>(h2b + lane * 8);
        __syncthreads();
        enc2_half(ah0, ah1, a2h);
    }
    __syncthreads();
    const bf16x8 aLh = *reinterpret_cast<const bf16x8*>(h2b + lane * 8);   // latent -> regs

    // ---------------- re-stage DECODER weights ----------------
    stageBh<2, 6>((u16*)(W + O_WHH3), w3hh, 256, tid);
    stageBh<1, 6>((u16*)(W + O_WIH3), w3ih, 256, tid);
    stageBh<2, 2>((u16*)(W + O_WIH4), w4ih, 16, tid);
    for (int i = tid; i < 64; i += BLOCKT)
        W[O_W4HHF + i] = w4hh[i] * ((((i >> 4) & 3) == 2) ? LOG2E2 : LOG2E);

    float c3[2][4];
#pragma unroll
    for (int ql = 0; ql < 2; ++ql)
#pragma unroll
        for (int r = 0; r < 4; ++r) c3[ql][r] = 0.f;
    float c4 = 0.f;
    const int u4 = lane & 3, mb = lane >> 2;
    __syncthreads();   // dec weights visible; enc reads all done before restage started

    const u16* Whh3hi = (const u16*)(W + O_WHH3);
    const u16* Wih3hi = (const u16*)(W + O_WIH3);
    const u16* Wih4hi = (const u16*)(W + O_WIH4);
    const float* W4hhF = W + O_W4HHF;
    const f32x4 bias4v = *reinterpret_cast<const f32x4*>(b4f + (quad << 2));

    // ---- hoist own-half Whh3 frags (64 VGPR; reuses dead enc whh1r regs) ----
    bf16x8 whh3r[2][4][2];
#pragma unroll
    for (int ql = 0; ql < 2; ++ql)
#pragma unroll
        for (int i = 0; i < 4; ++i) {
            const int nt = i * 4 + q0 + ql;
            whh3r[ql][i][0] = *reinterpret_cast<const bf16x8*>(Whh3hi + ((nt * 2 + 0) * 64 + lane) * 8);
            whh3r[ql][i][1] = *reinterpret_cast<const bf16x8*>(Whh3hi + ((nt * 2 + 1) * 64 + lane) * 8);
        }

    // dec1 for this half: 24 MFMA + 8 unitH, writes own h3 half
    auto dec1_half = [&](const bf16x8 ah0, const bf16x8 ah1) {
#pragma unroll
        for (int ql = 0; ql < 2; ++ql) {
            f32x4 acc[4];
#pragma unroll
            for (int i = 0; i < 4; ++i) {
                const int nt = i * 4 + q0 + ql;
                const bf16x8 bL = *reinterpret_cast<const bf16x8*>(Wih3hi + (nt * 64 + lane) * 8);
                f32x4 a = *reinterpret_cast<const f32x4*>(b3f + nt * 16 + (quad << 2));
                a = MFMA(bL, aLh, a);
                a = MFMA(whh3r[ql][i][0], ah0, a);
                a = MFMA(whh3r[ql][i][1], ah1, a);
                acc[i] = a;
            }
            const float h0 = unitH(acc[0][0], acc[1][0], acc[2][0], acc[3][0], c3[ql][0]);
            const float h1 = unitH(acc[0][1], acc[1][1], acc[2][1], acc[3][1], c3[ql][1]);
            const float h2 = unitH(acc[0][2], acc[1][2], acc[2][2], acc[3][2], c3[ql][2]);
            const float h3 = unitH(acc[0][3], acc[1][3], acc[2][3], acc[3][3], c3[ql][3]);
            u32x2 wv;
            wv.x = cvtpk2(h0, h1);
            wv.y = cvtpk2(h2, h3);
            *reinterpret_cast<u32x2*>(h1b + hbase + (wh << 9) + (ql << 8)) = wv;
        }
    };
    // dec2 (wh==1 only): 2 MFMA + transpose + 1 unitH + store
    auto dec2_step = [&](const bf16x8 ah0, const bf16x8 ah1, const float4 hv, int t) {
        f32x4 acc4 = bias4v;
#pragma unroll
        for (int r = 0; r < 4; ++r) {
            const float4 w4 = *reinterpret_cast<const float4*>(W4hhF + ((quad * 4 + r) << 2));
            float sa = acc4[r];
            sa = fmaf(w4.x, hv.x, sa);
            sa = fmaf(w4.y, hv.y, sa);
            sa = fmaf(w4.z, hv.z, sa);
            sa = fmaf(w4.w, hv.w, sa);
            acc4[r] = sa;
        }
        const bf16x8 w4f0 = *reinterpret_cast<const bf16x8*>(Wih4hi + (0 * 64 + lane) * 8);
        const bf16x8 w4f1 = *reinterpret_cast<const bf16x8*>(Wih4hi + (1 * 64 + lane) * 8);
        acc4 = MFMA(w4f0, ah0, acc4);
        acc4 = MFMA(w4f1, ah1, acc4);
        WB();
        *reinterpret_cast<f32x4*>(gbuf + (col << 4) + (quad << 2)) = acc4;   // wave-local
        WB();
        const float yi = gbuf[mb * 16 + u4];
        const float yf = gbuf[mb * 16 + 4 + u4];
        const float yg = gbuf[mb * 16 + 8 + u4];
        const float yo = gbuf[mb * 16 + 12 + u4];
        const float h = unitH(yi, yf, yg, yo, c4);
        out[((size_t)(b0w + mb) * TT + t) * IN + u4] = h;
        bufH4[mb * 4 + u4] = h;
    };

    {   // prologue: dec1[0] with h3[-1]=0
        const bf16x8 z8 = {};
        dec1_half(z8, z8);
    }
    __syncthreads();

    for (int t = 0; t < TT - 1; ++t) {
        const bf16x8 ah0 = *reinterpret_cast<const bf16x8*>(h1b + lane * 8);        // h3[t]
        const bf16x8 ah1 = *reinterpret_cast<const bf16x8*>(h1b + (64 + lane) * 8);
        float4 hv = {0.f, 0.f, 0.f, 0.f};
        if (wh) hv = *reinterpret_cast<const float4*>(bufH4 + (col << 2));          // h4[t-1]
        __syncthreads();   // alpha
        if (wh) dec2_step(ah0, ah1, hv, t);
        dec1_half(ah0, ah1);                         // writes h3[t+1] half
        __syncthreads();   // beta
    }
    {   // epilogue: dec2[TT-1]
        const bf16x8 ah0 = *reinterpret_cast<const bf16x8*>(h1b + lane * 8);
        const bf16x8 ah1 = *reinterpret_cast<const bf16x8*>(h1b + (64 + lane) * 8);
        if (wh) {
            const float4 hv = *reinterpret_cast<const float4*>(bufH4 + (col << 2));
            dec2_step(ah0, ah1, hv, TT - 1);
        }
    }
}

extern "C" void kernel_launch(void* const* d_in, const int* in_sizes, int n_in,
                              void* d_out, int out_size, void* d_ws, size_t ws_size,
                              hipStream_t stream) {
    (void)in_sizes; (void)n_in; (void)d_ws; (void)ws_size; (void)out_size;
    hipFuncSetAttribute(reinterpret_cast<const void*>(lstm_ae),
                        hipFuncAttributeMaxDynamicSharedMemorySize, SMEM_BYTES);
    const float* xi = (const float*)d_in[0];
    const float* w1ih = (const float*)d_in[1];
    const float* w1hh = (const float*)d_in[2];
    const float* b1i = (const float*)d_in[3];
    const float* b1h = (const float*)d_in[4];
    const float* w2ih = (const float*)d_in[5];
    const float* w2hh = (const float*)d_in[6];
    const float* b2i = (const float*)d_in[7];
    const float* b2h = (const float*)d_in[8];
    const float* w3ih = (const float*)d_in[9];
    const float* w3hh = (const float*)d_in[10];
    const float* b3i = (const float*)d_in[11];
    const float* b3h = (const float*)d_in[12];
    const float* w4ih = (const float*)d_in[13];
    const float* w4hh = (const float*)d_in[14];
    const float* b4i = (const float*)d_in[15];
    const float* b4h = (const float*)d_in[16];
    float* out = (float*)d_out;

    lstm_ae<<<dim3(BATCH / BPB), dim3(BLOCKT), SMEM_BYTES, stream>>>(
        xi, w1ih, w1hh, b1i, b1h, w2ih, w2hh, b2i, b2h,
        w3ih, w3hh, b3i, b3h, w4ih, w4hh, b4i, b4h, out);
}

// Round 8
// 286.142 us; speedup vs baseline: 1.3046x; 1.3046x over previous
//
#include <hip/hip_runtime.h>
#include <stdint.h>

// LSTM autoencoder B=32768 T=30 I=4 H=64 L=32, fp32 in/out.
// v20.1 = v20 (32x32x16 restructure; bench infra-failed, no counters) with
// VGPR hardening: role-exclusive c-state arrays merged into one cst[16]
// (enc: c1 for roles 0/1, c2 for role 2; dec: c3 for roles 0/1) -> ~32 VGPR
// off the worst-case path, safely under the 168-cap implied by
// __launch_bounds__(768) (12 waves/block -> >=3 waves/SIMD).
// Rationale (v14-v19): 16x16 tiles need 1KB weight fragment per 8K MACs ->
// 4 w/SIMD saturates the LDS read pipe (~12cyc x ~100 b128/group-step =
// 235-261us); 2 w/SIMD hoisted is latency-bound (247us); hoisting at
// 4 w/SIMD spills (v19 FETCH 316MB). mfma_f32_32x32x16_bf16 doubles
// MACs per operand-KB and halves MFMA count -> LDS traffic halves, no hoists.
// Structure: 32-batch clusters of 3 waves: w0/w1 = enc1/dec1 unit-halves
// (role=unit-half), w2 = enc2 (+dec2). 12 waves/block (768thr), 128
// batch/block, grid 256, 1 block/CU, 3 waves/SIMD (one wave per role per
// SIMD: LDS-heavy w2 overlaps compute-heavy w0/w1).
// Gate colocation: a 32-row tile = one gate x 32 units; the 4 gate-tiles of
// a unit-half share the (reg,lane) pattern -> unitH fully in-register.
// 2 syncthreads/step (read||alpha||write||beta), h images single-buffered.
// Math/quantization identical to v13-v19: 2-term x + 2-term bias in fold
// k-slots, log2e folded into weights, unitH = 5 exp2 + 2 rcp, 1-term bf16 h.
// absmax 9.77e-4.
// Layouts: C/D 32x32: col=lane&31, row=(reg&3)+8*(reg>>2)+4*(lane>>5)
// [m74/m101 HW-verified]; A/B: m|n=lane&31, k=(lane>>5)*8+j (generalized
// from verified 16x16 m120 pattern). dec2 keeps 16x16 (gates=16).

typedef unsigned short u16;
typedef unsigned int u32;
typedef __attribute__((ext_vector_type(8))) short bf16x8;
typedef __attribute__((ext_vector_type(4))) float f32x4;
typedef __attribute__((ext_vector_type(16))) float f32x16;
typedef __attribute__((ext_vector_type(4))) u32 u32x4;
typedef __attribute__((ext_vector_type(2))) u32 u32x2;

#define BATCH 32768
#define TT 30
#define IN 4
#define WAVES 12
#define BLOCKT (WAVES * 64)   // 768
#define MBC 32                // batches per cluster (3 waves)
#define NCL 4                 // clusters per block
#define BPB (NCL * MBC)       // 128 -> grid 256, 1 block/CU

#define LOG2E 1.4426950408889634f
#define LOG2E2 2.8853900817779268f

// ---- LDS word offsets ----
// enc weights
#define O_WHH1 0        // 256x64 bf16 = 8192 words (32 frags)
#define O_FOLD 8192     // 8 tiles x 512 u16 = 2048 words
#define O_WIH2 10240    // 128x64 = 4096 words
#define O_WHH2 14336    // 128x32 = 2048 -> 16384
// dec weights (restaged into same region)
#define O_WHH3 0        // 8192
#define O_WIH3 8192     // 256x32 = 4096 -> 12288
#define O_WIH4 12288    // 16x64 = 512 -> 12800
#define O_W4HHF 12800   // 64 -> 12864
// biases (persist across restage)
#define O_B2F 16384     // 128
#define O_B3F 16512     // 256
#define O_B4F 16768     // 16
#define O_BUFS 16784
// per-cluster: h1/h3 img 1024w | h2/latent 512w (gbuf aliases) | h4 128w
#define PBUF 1664
#define SMEM_WORDS (O_BUFS + NCL * PBUF)   // 23440
#define SMEM_BYTES (SMEM_WORDS * 4)        // 93760 <= 163840

#define WB() __builtin_amdgcn_wave_barrier()
// arg order: A = weight frag, B = data frag.
#define MFMA32(a, b, c) __builtin_amdgcn_mfma_f32_32x32x16_bf16((a), (b), (c), 0, 0, 0)
#define MFMA16(a, b, c) __builtin_amdgcn_mfma_f32_16x16x32_bf16((a), (b), (c), 0, 0, 0)

__device__ __forceinline__ u16 f2bf(float f) {   // RNE fp32->bf16 (staging)
    u32 u = __float_as_uint(f);
    u += 0x7fffu + ((u >> 16) & 1u);
    return (u16)(u >> 16);
}
__device__ __forceinline__ float bf2f(u16 v) { return __uint_as_float(((u32)v) << 16); }

__device__ __forceinline__ u32 cvtpk2(float a, float b) {   // packed RNE fp32x2->bf16x2
    u32 d;
    asm("v_cvt_pk_bf16_f32 %0, %1, %2" : "=v"(d) : "v"(a), "v"(b));
    return d;
}

// Fused LSTM cell update. Inputs pre-scaled (i,f,o by log2e; g by 2*log2e).
__device__ __forceinline__ float unitH(float yi, float yf, float yg, float yo, float& c) {
    const float ei = __builtin_amdgcn_exp2f(-yi);
    const float ef = __builtin_amdgcn_exp2f(-yf);
    const float eg = __builtin_amdgcn_exp2f(yg);
    const float eo = __builtin_amdgcn_exp2f(-yo);
    const float Z = (1.f + ei) * (1.f + eg);
    const float X = 1.f + ef;
    const float num = fmaf(eg - 1.f, X, c * Z);
    c = num * __builtin_amdgcn_rcpf(X * Z);
    const float ec = __builtin_amdgcn_exp2f(c * LOG2E2);
    return (ec - 1.f) * __builtin_amdgcn_rcpf((1.f + eo) * (1.f + ec));
}

// Stage fp32 W[N][K] -> bf16, 32x32x16 A-frag order, gate-scaled.
// frag idx = ((nt*KT16+kt)*64+l)*8+j; n = nt*32+(l&31), k = kt*16+(l>>5)*8+j
template <int KT16, int GS>
__device__ __forceinline__ void stage32(u16* dst, const float* src, int N, int tid) {
    const int K = KT16 * 16;
    const int total = N * K;
    for (int idx = tid; idx < total; idx += BLOCKT) {
        const int j = idx & 7;
        const int l = (idx >> 3) & 63;
        const int pr = idx >> 9;
        const int kt = pr % KT16;
        const int nt = pr / KT16;
        const int n = nt * 32 + (l & 31);
        const int k = kt * 16 + ((l >> 5) << 3) + j;
        const float s = (((n >> GS) & 3) == 2) ? LOG2E2 : LOG2E;
        dst[idx] = f2bf(src[n * K + k] * s);
    }
}

// Stage fp32 W[N][K] -> bf16, 16x16x32 frag order (dec2's W4ih), gate-scaled.
template <int KT, int GS>
__device__ __forceinline__ void stage16(u16* dst, const float* src, int N, int tid) {
    const int K = KT * 32;
    const int total = N * K;
    for (int idx = tid; idx < total; idx += BLOCKT) {
        const int j = idx & 7;
        const int l = (idx >> 3) & 63;
        const int pr = idx >> 9;
        const int kt = pr & (KT - 1);
        const int nt = pr / KT;
        const int n = (nt << 4) | (l & 15);
        const int k = (kt << 5) + ((l >> 4) << 3) + j;
        const float s = (((n >> GS) & 3) == 2) ? LOG2E2 : LOG2E;
        dst[idx] = f2bf(src[n * K + k] * s);
    }
}

// load a staged fragment: P = u16 base, IDX = fragment index
#define LD8(P, IDX) (*reinterpret_cast<const bf16x8*>((P) + ((IDX) * 64 + lane) * 8))

// init f32x16 acc from fp32 bias array at row base RB (rows RB..RB+31)
#define BINIT(DST, BP, RB)                                                               \
    _Pragma("unroll") for (int p_ = 0; p_ < 4; ++p_) {                                   \
        const f32x4 b_ = *reinterpret_cast<const f32x4*>((BP) + (RB) + p_ * 8 + 4 * hi); \
        (DST)[4 * p_ + 0] = b_[0]; (DST)[4 * p_ + 1] = b_[1];                            \
        (DST)[4 * p_ + 2] = b_[2]; (DST)[4 * p_ + 3] = b_[3];                            \
    }

// 16 unitH + packed h write. Writer cell r=4p+q: unit u = BKT*16+8p+4hi+q,
// batch c31. B-frag slot: kt=BKT+(p>>1), half=(p&1), j=4hi+q -> b64/p.
#define CELL16(AI, AF, AG, AO, CST, IMG, BKT)                                                        \
    _Pragma("unroll") for (int p_ = 0; p_ < 4; ++p_) {                                               \
        const float h0_ = unitH((AI)[4*p_+0], (AF)[4*p_+0], (AG)[4*p_+0], (AO)[4*p_+0], (CST)[4*p_+0]); \
        const float h1_ = unitH((AI)[4*p_+1], (AF)[4*p_+1], (AG)[4*p_+1], (AO)[4*p_+1], (CST)[4*p_+1]); \
        const float h2_ = unitH((AI)[4*p_+2], (AF)[4*p_+2], (AG)[4*p_+2], (AO)[4*p_+2], (CST)[4*p_+2]); \
        const float h3_ = unitH((AI)[4*p_+3], (AF)[4*p_+3], (AG)[4*p_+3], (AO)[4*p_+3], (CST)[4*p_+3]); \
        u32x2 wv_;                                                                                   \
        wv_.x = cvtpk2(h0_, h1_);                                                                    \
        wv_.y = cvtpk2(h2_, h3_);                                                                    \
        *reinterpret_cast<u32x2*>((IMG) + (((BKT) + (p_ >> 1)) * 64 + (p_ & 1) * 32 + c31) * 8 + 4 * hi) = wv_; \
    }

// enc1 gate-tile G (rows = gate G, units role*32..+31): fold + 4x Whh1
#define E1G(DST, G) {                                                  \
        f32x16 a_ = MFMA32(foldr[G], xB, z16);                         \
        a_ = MFMA32(LD8(Whh1p, (2 * (G) + role) * 4 + 0), h1B0, a_);   \
        a_ = MFMA32(LD8(Whh1p, (2 * (G) + role) * 4 + 1), h1B1, a_);   \
        a_ = MFMA32(LD8(Whh1p, (2 * (G) + role) * 4 + 2), h1B2, a_);   \
        a_ = MFMA32(LD8(Whh1p, (2 * (G) + role) * 4 + 3), h1B3, a_);   \
        DST = a_; }

// enc2 gate-tile G (rows = gate G, units 0..31)
#define E2G(DST, G) {                                                  \
        f32x16 a_; BINIT(a_, b2f, (G) * 32)                            \
        a_ = MFMA32(LD8(Wih2p, (G) * 4 + 0), h1B0, a_);                \
        a_ = MFMA32(LD8(Wih2p, (G) * 4 + 1), h1B1, a_);                \
        a_ = MFMA32(LD8(Wih2p, (G) * 4 + 2), h1B2, a_);                \
        a_ = MFMA32(LD8(Wih2p, (G) * 4 + 3), h1B3, a_);                \
        a_ = MFMA32(LD8(Whh2p, (G) * 2 + 0), h2B0, a_);                \
        a_ = MFMA32(LD8(Whh2p, (G) * 2 + 1), h2B1, a_);                \
        DST = a_; }

// dec1 gate-tile G: bias + 2x Wih3(latent) + 4x Whh3
#define D1G(DST, G) {                                                  \
        f32x16 a_; BINIT(a_, b3f, (2 * (G) + role) * 32)               \
        a_ = MFMA32(LD8(Wih3p, (2 * (G) + role) * 2 + 0), latB0, a_);  \
        a_ = MFMA32(LD8(Wih3p, (2 * (G) + role) * 2 + 1), latB1, a_);  \
        a_ = MFMA32(LD8(Whh3p, (2 * (G) + role) * 4 + 0), h3B0, a_);   \
        a_ = MFMA32(LD8(Whh3p, (2 * (G) + role) * 4 + 1), h3B1, a_);   \
        a_ = MFMA32(LD8(Whh3p, (2 * (G) + role) * 4 + 2), h3B2, a_);   \
        a_ = MFMA32(LD8(Whh3p, (2 * (G) + role) * 4 + 3), h3B3, a_);   \
        DST = a_; }
// dec1 prologue (h3[-1]=0): skip Whh3
#define D1G0(DST, G) {                                                 \
        f32x16 a_; BINIT(a_, b3f, (2 * (G) + role) * 32)               \
        a_ = MFMA32(LD8(Wih3p, (2 * (G) + role) * 2 + 0), latB0, a_);  \
        a_ = MFMA32(LD8(Wih3p, (2 * (G) + role) * 2 + 1), latB1, a_);  \
        DST = a_; }

// dec2 B-frag address in the h3 image (16x16 consumer of 32-format image)
#define D2ADDR(M, BH) ((((2 * (M) + (quad >> 1)) * 64) + (quad & 1) * 32 + (BH) * 16 + col16) * 8)

// dec2 body for timestep T (role 2): 2 batch-halves
#define DEC2BODY(T) {                                                                   \
        f32x4 a0 = b4v, a1 = b4v;                                                       \
        _Pragma("unroll") for (int r_ = 0; r_ < 4; ++r_) {                              \
            float s0 = a0[r_], s1 = a1[r_];                                             \
            s0 = fmaf(w4r[r_].x, hv0.x, s0); s0 = fmaf(w4r[r_].y, hv0.y, s0);           \
            s0 = fmaf(w4r[r_].z, hv0.z, s0); s0 = fmaf(w4r[r_].w, hv0.w, s0);           \
            s1 = fmaf(w4r[r_].x, hv1.x, s1); s1 = fmaf(w4r[r_].y, hv1.y, s1);           \
            s1 = fmaf(w4r[r_].z, hv1.z, s1); s1 = fmaf(w4r[r_].w, hv1.w, s1);           \
            a0[r_] = s0; a1[r_] = s1;                                                   \
        }                                                                               \
        a0 = MFMA16(w4a0, dB00, a0); a0 = MFMA16(w4a1, dB10, a0);                       \
        a1 = MFMA16(w4a0, dB01, a1); a1 = MFMA16(w4a1, dB11, a1);                       \
        WB();                                                                           \
        *reinterpret_cast<f32x4*>(gbuf + col16 * 16 + quad * 4) = a0;                   \
        *reinterpret_cast<f32x4*>(gbuf + (16 + col16) * 16 + quad * 4) = a1;            \
        WB();                                                                           \
        {                                                                               \
            const int u4_ = lane & 3, mb_ = lane >> 2;                                  \
            const float h0_ = unitH(gbuf[mb_ * 16 + u4_], gbuf[mb_ * 16 + 4 + u4_],     \
                                    gbuf[mb_ * 16 + 8 + u4_], gbuf[mb_ * 16 + 12 + u4_], c4a); \
            out[((size_t)(b0w + mb_) * TT + (T)) * IN + u4_] = h0_;                     \
            bufH4[mb_ * 4 + u4_] = h0_;                                                 \
            const int b1_ = 16 + mb_;                                                   \
            const float h1_ = unitH(gbuf[b1_ * 16 + u4_], gbuf[b1_ * 16 + 4 + u4_],     \
                                    gbuf[b1_ * 16 + 8 + u4_], gbuf[b1_ * 16 + 12 + u4_], c4b); \
            out[((size_t)(b0w + b1_) * TT + (T)) * IN + u4_] = h1_;                     \
            bufH4[b1_ * 4 + u4_] = h1_;                                                 \
        }                                                                               \
        WB(); }

__global__ __launch_bounds__(BLOCKT)
void lstm_ae(
    const float* __restrict__ x,
    const float* __restrict__ w1ih, const float* __restrict__ w1hh,
    const float* __restrict__ b1i, const float* __restrict__ b1h,
    const float* __restrict__ w2ih, const float* __restrict__ w2hh,
    const float* __restrict__ b2i, const float* __restrict__ b2h,
    const float* __restrict__ w3ih, const float* __restrict__ w3hh,
    const float* __restrict__ b3i, const float* __restrict__ b3h,
    const float* __restrict__ w4ih, const float* __restrict__ w4hh,
    const float* __restrict__ b4i, const float* __restrict__ b4h,
    float* __restrict__ out) {
    extern __shared__ float smem[];
    float* W = smem;

    const int tid = threadIdx.x;
    const int wave = tid >> 6, lane = tid & 63;
    const int cl = wave / 3, role = wave % 3;   // 4 clusters x {enc1-ub0, enc1-ub1, enc2}
    const int c31 = lane & 31, hi = lane >> 5;
    const int col16 = lane & 15, quad = lane >> 4;

    float* pb = smem + O_BUFS + cl * PBUF;
    u16* h1img = (u16*)pb;            // 2048 u16: h1 (enc) / h3 (dec)
    u16* h2img = (u16*)(pb + 1024);   // 1024 u16: h2 / latent
    float* gbuf = pb + 1024;          // 512 f: dec2 transpose (aliases h2img)
    float* bufH4 = pb + 1536;         // 128 f: dec2 h feedback

    const int b0w = blockIdx.x * BPB + cl * MBC;

    // ---------------- stage ENCODER weights + biases ----------------
    stage32<4, 6>((u16*)(W + O_WHH1), w1hh, 256, tid);
    stage32<4, 5>((u16*)(W + O_WIH2), w2ih, 128, tid);
    stage32<2, 5>((u16*)(W + O_WHH2), w2hh, 128, tid);
    {   // fold A-frags: lo lanes [whi x4 | whi x4]; hi lanes [wlo x4 | bhi blo 0 0]
        u16* F = (u16*)(W + O_FOLD);
        for (int idx = tid; idx < 4096; idx += BLOCKT) {
            const int j = idx & 7;
            const int l = (idx >> 3) & 63;
            const int nt = idx >> 9;
            const int m = nt * 32 + (l & 31);
            const int hif = l >> 5;
            const float sc = ((m >> 6) == 2) ? LOG2E2 : LOG2E;
            u16 v = 0;
            if (!hif) {
                v = f2bf(w1ih[m * 4 + (j & 3)] * sc);
            } else if (j < 4) {
                const float w = w1ih[m * 4 + j] * sc;
                v = f2bf(w - bf2f(f2bf(w)));
            } else if (j == 4) {
                v = f2bf((b1i[m] + b1h[m]) * sc);
            } else if (j == 5) {
                const float b = (b1i[m] + b1h[m]) * sc;
                v = f2bf(b - bf2f(f2bf(b)));
            }
            F[idx] = v;
        }
    }
    float* b2f = W + O_B2F;
    float* b3f = W + O_B3F;
    float* b4f = W + O_B4F;
    for (int i = tid; i < 128; i += BLOCKT)
        b2f[i] = (b2i[i] + b2h[i]) * (((i >> 5) == 2) ? LOG2E2 : LOG2E);
    for (int i = tid; i < 256; i += BLOCKT)
        b3f[i] = (b3i[i] + b3h[i]) * (((i >> 6) == 2) ? LOG2E2 : LOG2E);
    for (int i = tid; i < 16; i += BLOCKT)
        b4f[i] = (b4i[i] + b4h[i]) * (((i >> 2) == 2) ? LOG2E2 : LOG2E);
    if (role == 2) {   // zero own h2 (h1 needs no zero: prologue writes full image)
        u32* z = (u32*)h2img;
        for (int i = lane; i < 512; i += 64) z[i] = 0u;
    }
    __syncthreads();

    const u16* Whh1p = (const u16*)(W + O_WHH1);
    const u16* Wih2p = (const u16*)(W + O_WIH2);
    const u16* Whh2p = (const u16*)(W + O_WHH2);
    const u16* FOLDp = (const u16*)(W + O_FOLD);

    const f32x16 z16 = {0.f, 0.f, 0.f, 0.f, 0.f, 0.f, 0.f, 0.f,
                        0.f, 0.f, 0.f, 0.f, 0.f, 0.f, 0.f, 0.f};
    // cst: role<2 -> c1 (enc1 cell state); role==2 -> c2 (enc2 cell state).
    // Re-zeroed for dec phase (role<2 -> c3). Merged to cut VGPR pressure.
    float cst[16];
#pragma unroll
    for (int r = 0; r < 16; ++r) cst[r] = 0.f;

    bf16x8 foldr[4] = {};
    if (role < 2) {
#pragma unroll
        for (int g = 0; g < 4; ++g) foldr[g] = LD8(FOLDp, 2 * g + role);
    }

    float4 xcur = {0.f, 0.f, 0.f, 0.f};
    if (role < 2)
        xcur = *reinterpret_cast<const float4*>(x + ((size_t)(b0w + c31) * TT + 0) * IN);

    // x B-frag: lo lanes [xhi x4 | xlo x4]; hi lanes [xhi x4 | 1.0 1.0 0 0]
    auto buildX = [&](const float4 xc) -> bf16x8 {
        const u32 h01 = cvtpk2(xc.x, xc.y);
        const u32 h23 = cvtpk2(xc.z, xc.w);
        const float r0 = xc.x - __uint_as_float(h01 << 16);
        const float r1 = xc.y - __uint_as_float(h01 & 0xffff0000u);
        const float r2 = xc.z - __uint_as_float(h23 << 16);
        const float r3 = xc.w - __uint_as_float(h23 & 0xffff0000u);
        const u32 l01 = cvtpk2(r0, r1);
        const u32 l23 = cvtpk2(r2, r3);
        u32x4 v;
        v.x = h01;
        v.y = h23;
        v.z = hi ? 0x3F803F80u : l01;
        v.w = hi ? 0u : l23;
        return __builtin_bit_cast(bf16x8, v);
    };

    // ================= encoder =================
    if (role < 2) {   // prologue: enc1[0], h1[-1]=0 (fold term only)
        const bf16x8 xB = buildX(xcur);
        xcur = *reinterpret_cast<const float4*>(x + ((size_t)(b0w + c31) * TT + 1) * IN);
        f32x16 aI = MFMA32(foldr[0], xB, z16);
        f32x16 aF = MFMA32(foldr[1], xB, z16);
        f32x16 aG = MFMA32(foldr[2], xB, z16);
        f32x16 aO = MFMA32(foldr[3], xB, z16);
        CELL16(aI, aF, aG, aO, cst, h1img, 2 * role)
    }
    __syncthreads();

    for (int t = 0; t < TT - 1; ++t) {
        // reads (before alpha)
        const bf16x8 h1B0 = *reinterpret_cast<const bf16x8*>(h1img + (0 * 64 + lane) * 8);
        const bf16x8 h1B1 = *reinterpret_cast<const bf16x8*>(h1img + (1 * 64 + lane) * 8);
        const bf16x8 h1B2 = *reinterpret_cast<const bf16x8*>(h1img + (2 * 64 + lane) * 8);
        const bf16x8 h1B3 = *reinterpret_cast<const bf16x8*>(h1img + (3 * 64 + lane) * 8);
        bf16x8 h2B0 = {}, h2B1 = {};
        if (role == 2) {
            h2B0 = *reinterpret_cast<const bf16x8*>(h2img + (0 * 64 + lane) * 8);
            h2B1 = *reinterpret_cast<const bf16x8*>(h2img + (1 * 64 + lane) * 8);
        }
        __syncthreads();   // alpha
        if (role == 2) {   // enc2[t]
            f32x16 aI, aF, aG, aO;
            E2G(aI, 0) E2G(aF, 1) E2G(aG, 2) E2G(aO, 3)
            CELL16(aI, aF, aG, aO, cst, h2img, 0)
        } else {           // enc1[t+1]
            const bf16x8 xB = buildX(xcur);
            const int tn = (t + 2 < TT) ? t + 2 : TT - 1;
            xcur = *reinterpret_cast<const float4*>(x + ((size_t)(b0w + c31) * TT + tn) * IN);
            f32x16 aI, aF, aG, aO;
            E1G(aI, 0) E1G(aF, 1) E1G(aG, 2) E1G(aO, 3)
            CELL16(aI, aF, aG, aO, cst, h1img, 2 * role)
        }
        __syncthreads();   // beta
    }
    if (role == 2) {   // epilogue: enc2[TT-1] -> latent in h2img
        const bf16x8 h1B0 = *reinterpret_cast<const bf16x8*>(h1img + (0 * 64 + lane) * 8);
        const bf16x8 h1B1 = *reinterpret_cast<const bf16x8*>(h1img + (1 * 64 + lane) * 8);
        const bf16x8 h1B2 = *reinterpret_cast<const bf16x8*>(h1img + (2 * 64 + lane) * 8);
        const bf16x8 h1B3 = *reinterpret_cast<const bf16x8*>(h1img + (3 * 64 + lane) * 8);
        const bf16x8 h2B0 = *reinterpret_cast<const bf16x8*>(h2img + (0 * 64 + lane) * 8);
        const bf16x8 h2B1 = *reinterpret_cast<const bf16x8*>(h2img + (1 * 64 + lane) * 8);
        f32x16 aI, aF, aG, aO;
        E2G(aI, 0) E2G(aF, 1) E2G(aG, 2) E2G(aO, 3)
        CELL16(aI, aF, aG, aO, cst, h2img, 0)
    }
    __syncthreads();   // latent visible

    // ---------------- re-stage DECODER weights + hoists ----------------
    stage32<4, 6>((u16*)(W + O_WHH3), w3hh, 256, tid);
    stage32<2, 6>((u16*)(W + O_WIH3), w3ih, 256, tid);
    stage16<2, 2>((u16*)(W + O_WIH4), w4ih, 16, tid);
    for (int i = tid; i < 64; i += BLOCKT)
        W[O_W4HHF + i] = w4hh[i] * ((((i >> 4) & 3) == 2) ? LOG2E2 : LOG2E);

    float c4a = 0.f, c4b = 0.f;
    bf16x8 latB0 = {}, latB1 = {};
    if (role < 2) {   // latent hoist (h2img untouched by restage)
        latB0 = *reinterpret_cast<const bf16x8*>(h2img + (0 * 64 + lane) * 8);
        latB1 = *reinterpret_cast<const bf16x8*>(h2img + (1 * 64 + lane) * 8);
    } else {
        for (int i = lane; i < 128; i += 64) bufH4[i] = 0.f;
    }
#pragma unroll
    for (int r = 0; r < 16; ++r) cst[r] = 0.f;   // re-zero: dec c3 (role<2)
    __syncthreads();   // dec weights visible

    const u16* Whh3p = (const u16*)(W + O_WHH3);
    const u16* Wih3p = (const u16*)(W + O_WIH3);
    const u16* Wih4p = (const u16*)(W + O_WIH4);
    const float* W4hhF = W + O_W4HHF;
    bf16x8 w4a0 = {}, w4a1 = {};
    f32x4 b4v = {0.f, 0.f, 0.f, 0.f};
    float4 w4r[4] = {};
    if (role == 2) {   // dec2 hoists (tiny)
        w4a0 = LD8(Wih4p, 0);
        w4a1 = LD8(Wih4p, 1);
        b4v = *reinterpret_cast<const f32x4*>(b4f + quad * 4);
#pragma unroll
        for (int r = 0; r < 4; ++r)
            w4r[r] = *reinterpret_cast<const float4*>(W4hhF + (quad * 4 + r) * 4);
    }

    // ================= decoder =================
    if (role < 2) {   // prologue: dec1[0], h3[-1]=0
        f32x16 aI, aF, aG, aO;
        D1G0(aI, 0) D1G0(aF, 1) D1G0(aG, 2) D1G0(aO, 3)
        CELL16(aI, aF, aG, aO, cst, h1img, 2 * role)
    }
    __syncthreads();

    for (int t = 0; t < TT - 1; ++t) {
        bf16x8 h3B0 = {}, h3B1 = {}, h3B2 = {}, h3B3 = {};
        bf16x8 dB00 = {}, dB10 = {}, dB01 = {}, dB11 = {};
        float4 hv0 = {0.f, 0.f, 0.f, 0.f}, hv1 = {0.f, 0.f, 0.f, 0.f};
        if (role < 2) {
            h3B0 = *reinterpret_cast<const bf16x8*>(h1img + (0 * 64 + lane) * 8);
            h3B1 = *reinterpret_cast<const bf16x8*>(h1img + (1 * 64 + lane) * 8);
            h3B2 = *reinterpret_cast<const bf16x8*>(h1img + (2 * 64 + lane) * 8);
            h3B3 = *reinterpret_cast<const bf16x8*>(h1img + (3 * 64 + lane) * 8);
        } else {
            dB00 = *reinterpret_cast<const bf16x8*>(h1img + D2ADDR(0, 0));
            dB10 = *reinterpret_cast<const bf16x8*>(h1img + D2ADDR(1, 0));
            dB01 = *reinterpret_cast<const bf16x8*>(h1img + D2ADDR(0, 1));
            dB11 = *reinterpret_cast<const bf16x8*>(h1img + D2ADDR(1, 1));
            hv0 = *reinterpret_cast<const float4*>(bufH4 + col16 * 4);
            hv1 = *reinterpret_cast<const float4*>(bufH4 + (16 + col16) * 4);
        }
        __syncthreads();   // alpha
        if (role == 2) {   // dec2[t]
            DEC2BODY(t)
        } else {           // dec1[t+1]
            f32x16 aI, aF, aG, aO;
            D1G(aI, 0) D1G(aF, 1) D1G(aG, 2) D1G(aO, 3)
            CELL16(aI, aF, aG, aO, cst, h1img, 2 * role)
        }
        __syncthreads();   // beta
    }
    if (role == 2) {   // epilogue: dec2[TT-1]
        const bf16x8 dB00 = *reinterpret_cast<const bf16x8*>(h1img + D2ADDR(0, 0));
        const bf16x8 dB10 = *reinterpret_cast<const bf16x8*>(h1img + D2ADDR(1, 0));
        const bf16x8 dB01 = *reinterpret_cast<const bf16x8*>(h1img + D2ADDR(0, 1));
        const bf16x8 dB11 = *reinterpret_cast<const bf16x8*>(h1img + D2ADDR(1, 1));
        const float4 hv0 = *reinterpret_cast<const float4*>(bufH4 + col16 * 4);
        const float4 hv1 = *reinterpret_cast<const float4*>(bufH4 + (16 + col16) * 4);
        DEC2BODY(TT - 1)
    }
}

extern "C" void kernel_launch(void* const* d_in, const int* in_sizes, int n_in,
                              void* d_out, int out_size, void* d_ws, size_t ws_size,
                              hipStream_t stream) {
    (void)in_sizes; (void)n_in; (void)d_ws; (void)ws_size; (void)out_size;
    hipFuncSetAttribute(reinterpret_cast<const void*>(lstm_ae),
                        hipFuncAttributeMaxDynamicSharedMemorySize, SMEM_BYTES);
    const float* xi = (const float*)d_in[0];
    const float* w1ih = (const float*)d_in[1];
    const float* w1hh = (const float*)d_in[2];
    const float* b1i = (const float*)d_in[3];
    const float* b1h = (const float*)d_in[4];
    const float* w2ih = (const float*)d_in[5];
    const float* w2hh = (const float*)d_in[6];
    const float* b2i = (const float*)d_in[7];
    const float* b2h = (const float*)d_in[8];
    const float* w3ih = (const float*)d_in[9];
    const float* w3hh = (const float*)d_in[10];
    const float* b3i = (const float*)d_in[11];
    const float* b3h = (const float*)d_in[12];
    const float* w4ih = (const float*)d_in[13];
    const float* w4hh = (const float*)d_in[14];
    const float* b4i = (const float*)d_in[15];
    const float* b4h = (const float*)d_in[16];
    float* out = (float*)d_out;

    lstm_ae<<<dim3(BATCH / BPB), dim3(BLOCKT), SMEM_BYTES, stream>>>(
        xi, w1ih, w1hh, b1i, b1h, w2ih, w2hh, b2i, b2h,
        w3ih, w3hh, b3i, b3h, w4ih, w4hh, b4i, b4h, out);
}